// Round 2
// baseline (417.032 us; speedup 1.0000x reference)
//
#include <hip/hip_runtime.h>

// ---------------------------------------------------------------------------
// Native Sparse Attention (B=2, H=8, S=2048, D=64) — exact fp32 implementation
// Tile = (bh, qb): 64 queries. 512 threads = 8 waves, wave owns 8 queries.
// ---------------------------------------------------------------------------

constexpr int SS   = 2048;
constexpr int DD   = 64;
constexpr int NBLK = 32;   // S / BLOCK_SIZE
constexpr int BS   = 64;   // BLOCK_SIZE
constexpr int SNB  = 8;    // NUM_SELECTED_BLOCKS
constexpr int KKEEP = 256; // min(NUM_SELECTED_TOKENS*SNB, SNB*BS)
constexpr float SCALE  = 0.125f;   // 1/sqrt(64)
constexpr float NEGINF = -1e30f;

#define DEV __device__ __forceinline__

DEV float readlane_f(float x, int l) {
  return __int_as_float(__builtin_amdgcn_readlane(__float_as_int(x), l));
}
DEV float wave_max(float x) {
#pragma unroll
  for (int off = 32; off > 0; off >>= 1) x = fmaxf(x, __shfl_xor(x, off, 64));
  return x;
}
DEV float wave_sum(float x) {
#pragma unroll
  for (int off = 32; off > 0; off >>= 1) x += __shfl_xor(x, off, 64);
  return x;
}
// monotone key <-> float (ascending). key2f(f2key(x)) == x for all finite x.
DEV float key2f(unsigned kk) {
  unsigned u = (kk & 0x80000000u) ? (kk & 0x7fffffffu) : ~kk;
  return __uint_as_float(u);
}

// stage one 64x64 fp32 block (row-major, row stride DD) into LDS [64][65]
DEV void stage64(float dst[BS][65], const float* __restrict__ src, int tid) {
  const int r  = tid >> 4;   // 0..31
  const int c4 = tid & 15;   // 0..15
  const float4 a = *(const float4*)(src + r * DD + c4 * 4);
  const float4 b = *(const float4*)(src + (r + 32) * DD + c4 * 4);
  const int c = c4 * 4;
  dst[r][c] = a.x; dst[r][c + 1] = a.y; dst[r][c + 2] = a.z; dst[r][c + 3] = a.w;
  dst[r + 32][c] = b.x; dst[r + 32][c + 1] = b.y; dst[r + 32][c + 2] = b.z; dst[r + 32][c + 3] = b.w;
}

// ---------------------------------------------------------------------------
// Kernel 1: per-block means of K and V  -> ws
// grid (NBLK, B*H), 64 threads (thread = dim)
// ---------------------------------------------------------------------------
__global__ __launch_bounds__(64) void nsa_means(const float* __restrict__ k,
                                                const float* __restrict__ v,
                                                float* __restrict__ kblk,
                                                float* __restrict__ vblk) {
  const int n = blockIdx.x, bh = blockIdx.y, d = threadIdx.x;
  const float* kb = k + ((size_t)bh * SS + (size_t)n * BS) * DD;
  const float* vb = v + ((size_t)bh * SS + (size_t)n * BS) * DD;
  float sk = 0.f, sv = 0.f;
  for (int t = 0; t < BS; ++t) { sk += kb[t * DD + d]; sv += vb[t * DD + d]; }
  kblk[((size_t)bh * NBLK + n) * DD + d] = sk * (1.f / 64.f);
  vblk[((size_t)bh * NBLK + n) * DD + d] = sv * (1.f / 64.f);
}

// ---------------------------------------------------------------------------
// Kernel 2: main NSA kernel. grid (nb=32, B*H=16), 512 threads
// ---------------------------------------------------------------------------
__global__ __launch_bounds__(512) void nsa_main(
    const float* __restrict__ qg, const float* __restrict__ kg,
    const float* __restrict__ vg, const float* __restrict__ kblk,
    const float* __restrict__ vblk, float* __restrict__ outg) {
  const int qb   = blockIdx.x;
  const int bh   = blockIdx.y;
  const int tid  = threadIdx.x;
  const int w    = tid >> 6;
  const int lane = tid & 63;
  const int q0   = qb * BS;
  const size_t base = (size_t)bh * SS * DD;

  __shared__ float kv_s[BS][65];
  __shared__ float kb_s[NBLK][65];
  __shared__ float vb_s[NBLK][65];
  __shared__ float logc_s[BS][NBLK];
  __shared__ float k0_s[DD], v0_s[DD];
  __shared__ float sc_s[NBLK];
  __shared__ int   sel_s[SNB];

  // per-wave query rows in registers (lane = dim), output accumulator too
  float qreg[8], outr[8];
#pragma unroll
  for (int j = 0; j < 8; ++j)
    qreg[j] = qg[base + (size_t)(q0 + w * 8 + j) * DD + lane];

  {
    const float* kb = kblk + (size_t)bh * NBLK * DD;
    const float* vb = vblk + (size_t)bh * NBLK * DD;
    for (int i = tid; i < NBLK * DD; i += 512) {
      kb_s[i >> 6][i & 63] = kb[i];
      vb_s[i >> 6][i & 63] = vb[i];
    }
    if (tid < DD) { k0_s[tid] = kg[base + tid]; v0_s[tid] = vg[base + tid]; }
  }
  __syncthreads();

  // ---------------- compressed branch: QK ----------------
  {
    const int n = lane & 31;
    float acc[8] = {0, 0, 0, 0, 0, 0, 0, 0};
#pragma unroll 4
    for (int d = 0; d < DD; ++d) {
      const float kd = kb_s[n][d];
#pragma unroll
      for (int j = 0; j < 8; ++j) acc[j] = fmaf(readlane_f(qreg[j], d), kd, acc[j]);
    }
    if (lane < 32) {
#pragma unroll
      for (int j = 0; j < 8; ++j) logc_s[w * 8 + j][n] = acc[j] * SCALE;
    }
  }
  __syncthreads();

  // ---------------- block scores + top-8 ----------------
  if (tid < NBLK) {
    float s = NEGINF;
    if (tid <= qb) {
      float a = 0.f;
      for (int qq = 0; qq < BS; ++qq) a += logc_s[qq][tid];
      s = a * (1.f / 64.f);
    }
    sc_s[tid] = s;
  }
  __syncthreads();
  if (tid == 0) {
    unsigned taken = 0u;
    for (int t = 0; t < SNB; ++t) {
      float best = -3.4e38f; int bi = 0;
      for (int n = 0; n < NBLK; ++n)
        if (!((taken >> n) & 1u) && sc_s[n] > best) { best = sc_s[n]; bi = n; }
      taken |= 1u << bi;
      sel_s[t] = bi;
    }
  }
  __syncthreads();

  // ---------------- compressed softmax + PV ----------------
  {
    const int n = lane & 31;
#pragma unroll
    for (int j = 0; j < 8; ++j) {
      const bool valid = (lane < 32) && (n <= qb);
      const float l = valid ? logc_s[w * 8 + j][n] : NEGINF;
      const float m = wave_max(l);
      const float e = valid ? __expf(l - m) : 0.f;
      const float ssum = wave_sum(e);
      const float p = e / ssum;
      float acc = 0.f;
      for (int n2 = 0; n2 <= qb; ++n2)
        acc = fmaf(readlane_f(p, n2), vb_s[n2][lane], acc);
      outr[j] = acc;
    }
  }

  // ---------------- selected branch: QK over 8 blocks ----------------
  float L[8][SNB];  // [query][block], token = lane
#pragma unroll
  for (int sbi = 0; sbi < SNB; ++sbi) {
    __syncthreads();
    const int sb = sel_s[sbi];
    stage64(kv_s, kg + base + (size_t)sb * BS * DD, tid);
    __syncthreads();
    float acc[8] = {0, 0, 0, 0, 0, 0, 0, 0};
#pragma unroll 4
    for (int d = 0; d < DD; ++d) {
      const float kd = kv_s[lane][d];
#pragma unroll
      for (int j = 0; j < 8; ++j) acc[j] = fmaf(readlane_f(qreg[j], d), kd, acc[j]);
    }
    const int tok = sb * BS + lane;
#pragma unroll
    for (int j = 0; j < 8; ++j) {
      const int pos = q0 + w * 8 + j;
      L[j][sbi] = (tok <= pos) ? acc[j] * SCALE : NEGINF;
    }
  }

  // ---------------- selected: exact 256th-largest threshold + softmax ------
#pragma unroll
  for (int j = 0; j < 8; ++j) {
    // binary search over monotone key space: lo = max{T : #(v >= key2f(T)) >= 256}
    // overflow-safe upper midpoint: mid = ceil((lo+hi)/2), guarantees lo < mid <= hi
    unsigned lo = 0u, hi = 0xFFFFFFFFu;
    for (int it = 0; it < 33 && lo < hi; ++it) {
      const unsigned span = hi - lo;
      const unsigned mid = lo + (span >> 1) + (span & 1u);
      const float tf = key2f(mid);
      int c = 0;
#pragma unroll
      for (int i = 0; i < SNB; ++i) c += __popcll(__ballot(L[j][i] >= tf));
      if (c >= KKEEP) lo = mid; else hi = mid - 1u;
    }
    const float thr = key2f(lo);   // == exact a_256 of the 512 values
    float m = NEGINF;
#pragma unroll
    for (int i = 0; i < SNB; ++i) m = fmaxf(m, L[j][i]);
    m = wave_max(m);
    float s = 0.f;
#pragma unroll
    for (int i = 0; i < SNB; ++i) {
      const float e = (L[j][i] >= thr) ? __expf(L[j][i] - m) : 0.f;
      L[j][i] = e; s += e;
    }
    s = wave_sum(s);
    const float inv = 1.f / s;
#pragma unroll
    for (int i = 0; i < SNB; ++i) L[j][i] *= inv;
  }

  // ---------------- selected: PV ----------------
#pragma unroll
  for (int sbi = 0; sbi < SNB; ++sbi) {
    __syncthreads();
    const int sb = sel_s[sbi];
    stage64(kv_s, vg + base + (size_t)sb * BS * DD, tid);
    __syncthreads();
#pragma unroll 2
    for (int t = 0; t < BS; ++t) {
      const float vd = kv_s[t][lane];
#pragma unroll
      for (int j = 0; j < 8; ++j) outr[j] = fmaf(readlane_f(L[j][sbi], t), vd, outr[j]);
    }
  }

  // ---------------- window branch: QK over up to 3 blocks + global token ---
  float Lw[8][3];
  float l192[8], p192[8];
#pragma unroll
  for (int wi = 0; wi < 3; ++wi) {
    const int wb = qb - 2 + wi;
    if (wb >= 0) {  // block-uniform branch
      __syncthreads();
      stage64(kv_s, kg + base + (size_t)wb * BS * DD, tid);
      __syncthreads();
      float acc[8] = {0, 0, 0, 0, 0, 0, 0, 0};
#pragma unroll 4
      for (int d = 0; d < DD; ++d) {
        const float kd = kv_s[lane][d];
#pragma unroll
        for (int j = 0; j < 8; ++j) acc[j] = fmaf(readlane_f(qreg[j], d), kd, acc[j]);
      }
      const int tok = wb * BS + lane;
#pragma unroll
      for (int j = 0; j < 8; ++j) {
        const int pos = q0 + w * 8 + j;
        const bool valid = (tok <= pos) && ((pos - tok < 128) || (tok == 0));
        Lw[j][wi] = valid ? acc[j] * SCALE : NEGINF;
      }
    } else {
#pragma unroll
      for (int j = 0; j < 8; ++j) Lw[j][wi] = NEGINF;
    }
  }
  // global-token logit (only needed as extra column when qb >= 3)
#pragma unroll
  for (int j = 0; j < 8; ++j) {
    const float dot = wave_sum(qreg[j] * k0_s[lane]);
    l192[j] = (qb >= 3) ? dot * SCALE : NEGINF;
  }

  // ---------------- window softmax ----------------
#pragma unroll
  for (int j = 0; j < 8; ++j) {
    float m = fmaxf(fmaxf(Lw[j][0], Lw[j][1]), Lw[j][2]);
    m = wave_max(m);
    m = fmaxf(m, l192[j]);
    const float e0 = __expf(Lw[j][0] - m);
    const float e1 = __expf(Lw[j][1] - m);
    const float e2 = __expf(Lw[j][2] - m);
    float s = wave_sum(e0 + e1 + e2);
    const float e192 = (qb >= 3) ? __expf(l192[j] - m) : 0.f;
    s += e192;
    const float inv = 1.f / s;
    Lw[j][0] = e0 * inv; Lw[j][1] = e1 * inv; Lw[j][2] = e2 * inv;
    p192[j] = e192 * inv;
  }

  // ---------------- window PV ----------------
#pragma unroll
  for (int wi = 0; wi < 3; ++wi) {
    const int wb = qb - 2 + wi;
    if (wb >= 0) {
      __syncthreads();
      stage64(kv_s, vg + base + (size_t)wb * BS * DD, tid);
      __syncthreads();
#pragma unroll 2
      for (int t = 0; t < BS; ++t) {
        const float vd = kv_s[t][lane];
#pragma unroll
        for (int j = 0; j < 8; ++j) outr[j] = fmaf(readlane_f(Lw[j][wi], t), vd, outr[j]);
      }
    }
  }
  {
    const float v0 = v0_s[lane];
#pragma unroll
    for (int j = 0; j < 8; ++j) outr[j] = fmaf(p192[j], v0, outr[j]);
  }

  // ---------------- store (cmp + sel + win) / 3 ----------------
#pragma unroll
  for (int j = 0; j < 8; ++j)
    outg[base + (size_t)(q0 + w * 8 + j) * DD + lane] = outr[j] * (1.f / 3.f);
}

// ---------------------------------------------------------------------------
extern "C" void kernel_launch(void* const* d_in, const int* in_sizes, int n_in,
                              void* d_out, int out_size, void* d_ws, size_t ws_size,
                              hipStream_t stream) {
  (void)in_sizes; (void)n_in; (void)out_size; (void)ws_size;
  const float* q = (const float*)d_in[0];
  const float* k = (const float*)d_in[1];
  const float* v = (const float*)d_in[2];
  float* out = (float*)d_out;
  float* wsf = (float*)d_ws;
  float* kblk = wsf;                       // 16*32*64 floats
  float* vblk = wsf + 16 * NBLK * DD;      // 16*32*64 floats

  dim3 g1(NBLK, 16);
  nsa_means<<<g1, 64, 0, stream>>>(k, v, kblk, vblk);
  dim3 g2(NBLK, 16);
  nsa_main<<<g2, 512, 0, stream>>>(q, k, v, kblk, vblk, out);
}

// Round 3
// 127.583 us; speedup vs baseline: 3.2687x; 3.2687x over previous
//
#include <hip/hip_runtime.h>

// ---------------------------------------------------------------------------
// Native Sparse Attention (B=2, H=8, S=2048, D=64)
// Tile = (bh, qb): 64 queries. 512 threads = 8 waves, wave owns 8 queries.
// cmp branch + block selection: exact fp32 (selection-critical).
// sel/win QK: split-bf16 MFMA (QhKh + QhKl + QlKh), logit err ~1e-5.
// sel/win PV: bf16 MFMA (P_bf16 x V_bf16hi), err ~2e-3 << 0.053 budget.
// ---------------------------------------------------------------------------

constexpr int SS   = 2048;
constexpr int DD   = 64;
constexpr int NBLK = 32;
constexpr int BS   = 64;
constexpr int SNB  = 8;
constexpr int KKEEP = 256;
constexpr float SCALE  = 0.125f;
constexpr float NEGINF = -1e30f;

#define DEV __device__ __forceinline__

typedef __attribute__((ext_vector_type(8))) short s8_t;   // 8 x bf16 (4 VGPR)
typedef __attribute__((ext_vector_type(4))) float f4_t;   // MFMA C/D frag

union S8U  { uint4 u; s8_t s; };
union S8H  { unsigned short h[8]; s8_t s; };

DEV s8_t as_s8(uint4 u) { S8U x; x.u = u; return x.s; }

DEV float readlane_f(float x, int l) {
  return __int_as_float(__builtin_amdgcn_readlane(__float_as_int(x), l));
}
DEV float wave_max(float x) {
#pragma unroll
  for (int off = 32; off > 0; off >>= 1) x = fmaxf(x, __shfl_xor(x, off, 64));
  return x;
}
DEV float wave_sum(float x) {
#pragma unroll
  for (int off = 32; off > 0; off >>= 1) x += __shfl_xor(x, off, 64);
  return x;
}
// fp32 -> bf16 (RNE) and back
DEV unsigned short f2bh(float x) {
  unsigned u = __float_as_uint(x);
  unsigned r = u + 0x7FFFu + ((u >> 16) & 1u);
  return (unsigned short)(r >> 16);
}
DEV float bh2f(unsigned short h) { return __uint_as_float(((unsigned)h) << 16); }

DEV f4_t mfma16(s8_t a, s8_t b, f4_t c) {
  return __builtin_amdgcn_mfma_f32_16x16x32_bf16(a, b, c, 0, 0, 0);
}
// wave-local LDS fence: wave's own ds writes visible to its own ds reads
DEV void wave_fence() {
  asm volatile("s_waitcnt lgkmcnt(0)" ::: "memory");
  __builtin_amdgcn_sched_barrier(0);
}

// --- stage K block as split-bf16, row-major packed: [tok][dim-pairs], stride 40 uints
DEV void stageK(unsigned int* kh, unsigned int* kl, const float* __restrict__ src, int tid) {
  const int r = tid >> 4, c4 = tid & 15;
#pragma unroll
  for (int half = 0; half < 2; ++half) {
    const int row = r + half * 32;
    const float4 a = *(const float4*)(src + row * DD + c4 * 4);
    const float f[4] = {a.x, a.y, a.z, a.w};
    unsigned short h[4], l[4];
#pragma unroll
    for (int i = 0; i < 4; ++i) {
      h[i] = f2bh(f[i]);
      l[i] = f2bh(f[i] - bh2f(h[i]));
    }
    kh[row * 40 + c4 * 2]     = (unsigned)h[0] | ((unsigned)h[1] << 16);
    kh[row * 40 + c4 * 2 + 1] = (unsigned)h[2] | ((unsigned)h[3] << 16);
    kl[row * 40 + c4 * 2]     = (unsigned)l[0] | ((unsigned)l[1] << 16);
    kl[row * 40 + c4 * 2 + 1] = (unsigned)l[2] | ((unsigned)l[3] << 16);
  }
}

// --- stage V block transposed bf16-hi: vh[dim][tok-pairs], stride 40 uints
DEV void stageVT(unsigned int* vh, const float* __restrict__ src, int tid) {
  const int tp = tid & 31;   // token pair: toks 2tp, 2tp+1
  const int dg = tid >> 5;   // 0..15 : dims dg*4..+3
  const float4 a = *(const float4*)(src + (2 * tp) * DD + dg * 4);
  const float4 b = *(const float4*)(src + (2 * tp + 1) * DD + dg * 4);
  const float fa[4] = {a.x, a.y, a.z, a.w};
  const float fb[4] = {b.x, b.y, b.z, b.w};
#pragma unroll
  for (int i = 0; i < 4; ++i)
    vh[(dg * 4 + i) * 40 + tp] = (unsigned)f2bh(fa[i]) | ((unsigned)f2bh(fb[i]) << 16);
}

// --- QK mfma: C[q][tok] for 16 q-rows (8 valid) x 64 toks, K=64 dims split 3-term
DEV void qk_mfma(const unsigned int* kh, const unsigned int* kl,
                 const s8_t* qh, const s8_t* ql, int lane, f4_t c[4]) {
  const int qi = lane & 15, g = lane >> 4;
#pragma unroll
  for (int t = 0; t < 4; ++t) {
    f4_t acc = {0.f, 0.f, 0.f, 0.f};
#pragma unroll
    for (int ks = 0; ks < 2; ++ks) {
      const int off = (t * 16 + qi) * 40 + ks * 16 + g * 4;
      const s8_t Bh = as_s8(*(const uint4*)(kh + off));
      const s8_t Bl = as_s8(*(const uint4*)(kl + off));
      acc = mfma16(qh[ks], Bh, acc);
      acc = mfma16(qh[ks], Bl, acc);
      acc = mfma16(ql[ks], Bh, acc);
    }
    c[t] = acc;
  }
}

// --- redistribute C frags (rows 0..7) -> per-lane raw[j] (lane = token)
DEV void redist(const f4_t c[4], float* scw /*[8][68]*/, int lane, float raw[8]) {
  if (lane < 32) {
    const int g2 = lane >> 4, ci = lane & 15;
#pragma unroll
    for (int t = 0; t < 4; ++t)
#pragma unroll
      for (int r = 0; r < 4; ++r)
        scw[(g2 * 4 + r) * 68 + t * 16 + ci] = c[t][r];
  }
  wave_fence();
#pragma unroll
  for (int j = 0; j < 8; ++j) raw[j] = scw[j * 68 + lane];
}

// ---------------------------------------------------------------------------
__global__ __launch_bounds__(64) void nsa_means(const float* __restrict__ k,
                                                const float* __restrict__ v,
                                                float* __restrict__ kblk,
                                                float* __restrict__ vblk) {
  const int n = blockIdx.x, bh = blockIdx.y, d = threadIdx.x;
  const float* kb = k + ((size_t)bh * SS + (size_t)n * BS) * DD;
  const float* vb = v + ((size_t)bh * SS + (size_t)n * BS) * DD;
  float sk = 0.f, sv = 0.f;
  for (int t = 0; t < BS; ++t) { sk += kb[t * DD + d]; sv += vb[t * DD + d]; }
  kblk[((size_t)bh * NBLK + n) * DD + d] = sk * (1.f / 64.f);
  vblk[((size_t)bh * NBLK + n) * DD + d] = sv * (1.f / 64.f);
}

// ---------------------------------------------------------------------------
__global__ __launch_bounds__(512, 4) void nsa_main(
    const float* __restrict__ qg, const float* __restrict__ kg,
    const float* __restrict__ vg, const float* __restrict__ kblk,
    const float* __restrict__ vblk, float* __restrict__ outg) {
  const int qb   = blockIdx.x;
  const int bh   = blockIdx.y;
  const int tid  = threadIdx.x;
  const int w    = tid >> 6;
  const int lane = tid & 63;
  const int q0   = qb * BS;
  const size_t base = (size_t)bh * SS * DD;

  __shared__ __align__(16) unsigned int khl_s[2][64 * 40];  // 20480 B
  __shared__ __align__(16) float sc_f[8][8][68];            // 17408 B (per-wave scratch)
  __shared__ float kb_s[NBLK][65];                          // 8320
  __shared__ float vb_s[NBLK][65];                          // 8320
  __shared__ float logc_s[BS][NBLK];                        // 8192
  __shared__ float k0_s[DD], v0_s[DD];
  __shared__ float sc_s[NBLK];
  __shared__ int   sel_s[SNB];

  float* scw = &sc_f[w][0][0];
  unsigned short* scwu = (unsigned short*)scw;

  // ---- init: Q rows (lane=dim) + block means + global token ----
  float qreg[8];
#pragma unroll
  for (int j = 0; j < 8; ++j)
    qreg[j] = qg[base + (size_t)(q0 + w * 8 + j) * DD + lane];
  {
    const float* kb = kblk + (size_t)bh * NBLK * DD;
    const float* vb = vblk + (size_t)bh * NBLK * DD;
    for (int i = tid; i < NBLK * DD; i += 512) {
      kb_s[i >> 6][i & 63] = kb[i];
      vb_s[i >> 6][i & 63] = vb[i];
    }
    if (tid < DD) { k0_s[tid] = kg[base + tid]; v0_s[tid] = vg[base + tid]; }
  }
  __syncthreads();

  // ---- cmp QK: EXACT fp32 (selection-critical) ----
  {
    const int n = lane & 31;
    float acc[8] = {0, 0, 0, 0, 0, 0, 0, 0};
#pragma unroll 4
    for (int d = 0; d < DD; ++d) {
      const float kd = kb_s[n][d];
#pragma unroll
      for (int j = 0; j < 8; ++j) acc[j] = fmaf(readlane_f(qreg[j], d), kd, acc[j]);
    }
    if (lane < 32) {
#pragma unroll
      for (int j = 0; j < 8; ++j) logc_s[w * 8 + j][n] = acc[j] * SCALE;
    }
  }

  // ---- build Q A-fragments (bf16 hi/lo) from global ----
  s8_t qAh[2], qAl[2];
  {
    const int qi = lane & 15, g = lane >> 4;
    const float* qrow = qg + base + (size_t)(q0 + w * 8 + (qi < 8 ? qi : 0)) * DD;
#pragma unroll
    for (int ks = 0; ks < 2; ++ks) {
      float f[8];
      const float4 a = *(const float4*)(qrow + ks * 32 + g * 8);
      const float4 b = *(const float4*)(qrow + ks * 32 + g * 8 + 4);
      f[0] = a.x; f[1] = a.y; f[2] = a.z; f[3] = a.w;
      f[4] = b.x; f[5] = b.y; f[6] = b.z; f[7] = b.w;
      S8H hh, ll;
#pragma unroll
      for (int e = 0; e < 8; ++e) {
        const float x = (qi < 8) ? f[e] : 0.f;
        hh.h[e] = f2bh(x);
        ll.h[e] = f2bh(x - bh2f(hh.h[e]));
      }
      qAh[ks] = hh.s; qAl[ks] = ll.s;
    }
  }
  __syncthreads();

  // ---- block scores ----
  if (tid < NBLK) {
    float s = NEGINF;
    if (tid <= qb) {
      float a = 0.f;
      for (int qq = 0; qq < BS; ++qq) a += logc_s[qq][tid];
      s = a * (1.f / 64.f);
    }
    sc_s[tid] = s;
  }
  __syncthreads();
  // ---- top-8: wave-parallel argmax, exact lax.top_k tie-break (low index) ----
  if (w == 0) {
    float s = (lane < NBLK) ? sc_s[lane] : -3.4e38f;
    const int bi = lane;
    for (int t = 0; t < SNB; ++t) {
      float bs = s; int bb = bi;
#pragma unroll
      for (int off = 32; off > 0; off >>= 1) {
        const float os = __shfl_xor(bs, off, 64);
        const int   ob = __shfl_xor(bb, off, 64);
        if (os > bs || (os == bs && ob < bb)) { bs = os; bb = ob; }
      }
      if (lane == 0) sel_s[t] = bb;
      if (bi == bb) s = -3.4e38f;
    }
  }
  __syncthreads();

  // ---- sel QK: MFMA over 8 selected blocks ----
  float L[8][SNB];
#pragma unroll
  for (int sbi = 0; sbi < SNB; ++sbi) {
    __syncthreads();
    const int sb = sel_s[sbi];
    stageK(khl_s[0], khl_s[1], kg + base + (size_t)sb * BS * DD, tid);
    __syncthreads();
    f4_t c[4];
    qk_mfma(khl_s[0], khl_s[1], qAh, qAl, lane, c);
    float raw[8];
    redist(c, scw, lane, raw);
    const int tok = sb * BS + lane;
#pragma unroll
    for (int j = 0; j < 8; ++j) {
      const int pos = q0 + w * 8 + j;
      L[j][sbi] = (tok <= pos) ? raw[j] * SCALE : NEGINF;
    }
  }

  // ---- threshold (float-window search) + sel softmax -> packed bf16 P ----
  unsigned Lp[8][4];
#pragma unroll
  for (int j = 0; j < 8; ++j) {
    float m = L[j][0];
#pragma unroll
    for (int i = 1; i < SNB; ++i) m = fmaxf(m, L[j][i]);
    m = wave_max(m);
    float lo = m - 20.f, hi = m;
    int c0 = 0;
#pragma unroll
    for (int i = 0; i < SNB; ++i) c0 += __popcll(__ballot(L[j][i] >= lo));
    if (c0 >= KKEEP) {
      for (int it = 0; it < 20; ++it) {
        const float mid = 0.5f * (lo + hi);
        int cc = 0;
#pragma unroll
        for (int i = 0; i < SNB; ++i) cc += __popcll(__ballot(L[j][i] >= mid));
        if (cc >= KKEEP) lo = mid; else hi = mid;
      }
    }
    const float thr = lo;
    float s = 0.f;
#pragma unroll
    for (int i = 0; i < SNB; ++i) {
      const float e = (L[j][i] >= thr) ? __expf(L[j][i] - m) : 0.f;
      L[j][i] = e; s += e;
    }
    s = wave_sum(s);
    const float inv = 1.f / s;
#pragma unroll
    for (int ip = 0; ip < 4; ++ip)
      Lp[j][ip] = (unsigned)f2bh(L[j][2 * ip] * inv) |
                  ((unsigned)f2bh(L[j][2 * ip + 1] * inv) << 16);
  }

  // ---- sel PV: MFMA, accumulate into C-frag Of ----
  f4_t Of[4];
#pragma unroll
  for (int t = 0; t < 4; ++t) Of[t] = (f4_t){0.f, 0.f, 0.f, 0.f};
  const int qi = lane & 15, g = lane >> 4;
  const int qc = (qi < 8) ? qi : 0;
#pragma unroll
  for (int sbi = 0; sbi < SNB; ++sbi) {
    __syncthreads();
    const int sb = sel_s[sbi];
    stageVT(khl_s[0], vg + base + (size_t)sb * BS * DD, tid);
    __syncthreads();
    // write this block's P (bf16) to wave scratch, lane = token
#pragma unroll
    for (int j = 0; j < 8; ++j) {
      const unsigned u = Lp[j][sbi >> 1];
      scwu[j * 136 + lane] = (unsigned short)((sbi & 1) ? (u >> 16) : (u & 0xffffu));
    }
    wave_fence();
#pragma unroll
    for (int ks = 0; ks < 2; ++ks) {
      s8_t Pa = as_s8(*(const uint4*)(scwu + qc * 136 + ks * 32 + g * 8));
      if (qi >= 8) Pa = (s8_t)0;
#pragma unroll
      for (int t = 0; t < 4; ++t) {
        const s8_t Vh = as_s8(*(const uint4*)(&khl_s[0][(t * 16 + qi) * 40 + ks * 16 + g * 4]));
        Of[t] = mfma16(Pa, Vh, Of[t]);
      }
    }
  }

  // ---- win QK: MFMA over up to 3 blocks ----
  float Lw[8][3];
#pragma unroll
  for (int wi = 0; wi < 3; ++wi) {
    const int wb = qb - 2 + wi;
    if (wb >= 0) {
      __syncthreads();
      stageK(khl_s[0], khl_s[1], kg + base + (size_t)wb * BS * DD, tid);
      __syncthreads();
      f4_t c[4];
      qk_mfma(khl_s[0], khl_s[1], qAh, qAl, lane, c);
      float raw[8];
      redist(c, scw, lane, raw);
      const int tok = wb * BS + lane;
#pragma unroll
      for (int j = 0; j < 8; ++j) {
        const int pos = q0 + w * 8 + j;
        const bool valid = (tok <= pos) && ((pos - tok < 128) || (tok == 0));
        Lw[j][wi] = valid ? raw[j] * SCALE : NEGINF;
      }
    } else {
#pragma unroll
      for (int j = 0; j < 8; ++j) Lw[j][wi] = NEGINF;
    }
  }

  // ---- win softmax (+ exact global-token column when qb >= 3) ----
  unsigned Lwp[8][2];
  float p192[8];
#pragma unroll
  for (int j = 0; j < 8; ++j) {
    float l192 = NEGINF;
    if (qb >= 3) {
      const float qv = qg[base + (size_t)(q0 + w * 8 + j) * DD + lane];
      l192 = wave_sum(qv * k0_s[lane]) * SCALE;
    }
    float m = fmaxf(fmaxf(Lw[j][0], Lw[j][1]), Lw[j][2]);
    m = wave_max(m);
    m = fmaxf(m, l192);
    const float e0 = __expf(Lw[j][0] - m);
    const float e1 = __expf(Lw[j][1] - m);
    const float e2 = __expf(Lw[j][2] - m);
    float s = wave_sum(e0 + e1 + e2);
    const float e192 = (qb >= 3) ? __expf(l192 - m) : 0.f;
    s += e192;
    const float inv = 1.f / s;
    Lwp[j][0] = (unsigned)f2bh(e0 * inv) | ((unsigned)f2bh(e1 * inv) << 16);
    Lwp[j][1] = (unsigned)f2bh(e2 * inv);
    p192[j] = e192 * inv;
  }

  // ---- win PV: MFMA into same Of ----
#pragma unroll
  for (int wi = 0; wi < 3; ++wi) {
    const int wb = qb - 2 + wi;
    if (wb >= 0) {
      __syncthreads();
      stageVT(khl_s[0], vg + base + (size_t)wb * BS * DD, tid);
      __syncthreads();
#pragma unroll
      for (int j = 0; j < 8; ++j) {
        const unsigned u = Lwp[j][wi >> 1];
        scwu[j * 136 + lane] = (unsigned short)((wi & 1) ? (u >> 16) : (u & 0xffffu));
      }
      wave_fence();
#pragma unroll
      for (int ks = 0; ks < 2; ++ks) {
        s8_t Pa = as_s8(*(const uint4*)(scwu + qc * 136 + ks * 32 + g * 8));
        if (qi >= 8) Pa = (s8_t)0;
#pragma unroll
        for (int t = 0; t < 4; ++t) {
          const s8_t Vh = as_s8(*(const uint4*)(&khl_s[0][(t * 16 + qi) * 40 + ks * 16 + g * 4]));
          Of[t] = mfma16(Pa, Vh, Of[t]);
        }
      }
    }
  }

  // ---- redistribute Of -> lane=dim ----
  float ofin[8];
  redist(Of, scw, lane, ofin);

  // ---- cmp softmax + PV (exact, from persistent logc_s / vb_s) ----
  float cmp_out[8];
  {
    const int n = lane & 31;
#pragma unroll
    for (int j = 0; j < 8; ++j) {
      const bool valid = (lane < 32) && (n <= qb);
      const float l = valid ? logc_s[w * 8 + j][n] : NEGINF;
      const float m = wave_max(l);
      const float e = valid ? __expf(l - m) : 0.f;
      const float ssum = wave_sum(e);
      const float p = e / ssum;
      float acc = 0.f;
      for (int n2 = 0; n2 <= qb; ++n2)
        acc = fmaf(readlane_f(p, n2), vb_s[n2][lane], acc);
      cmp_out[j] = acc;
    }
  }

  // ---- store (cmp + sel + win)/3 ----
#pragma unroll
  for (int j = 0; j < 8; ++j)
    outg[base + (size_t)(q0 + w * 8 + j) * DD + lane] =
        (ofin[j] + cmp_out[j] + fmaf(p192[j], v0_s[lane], 0.f)) * (1.f / 3.f);
}

// ---------------------------------------------------------------------------
extern "C" void kernel_launch(void* const* d_in, const int* in_sizes, int n_in,
                              void* d_out, int out_size, void* d_ws, size_t ws_size,
                              hipStream_t stream) {
  (void)in_sizes; (void)n_in; (void)out_size; (void)ws_size;
  const float* q = (const float*)d_in[0];
  const float* k = (const float*)d_in[1];
  const float* v = (const float*)d_in[2];
  float* out = (float*)d_out;
  float* wsf = (float*)d_ws;
  float* kblk = wsf;
  float* vblk = wsf + 16 * NBLK * DD;

  dim3 g1(NBLK, 16);
  nsa_means<<<g1, 64, 0, stream>>>(k, v, kblk, vblk);
  dim3 g2(NBLK, 16);
  nsa_main<<<g2, 512, 0, stream>>>(q, k, v, kblk, vblk, out);
}